// Round 4
// baseline (172.749 us; speedup 1.0000x reference)
//
#include <hip/hip_runtime.h>

typedef __bf16 bf16x8 __attribute__((ext_vector_type(8)));
typedef __bf16 bf16x4 __attribute__((ext_vector_type(4)));
typedef float  f32x4  __attribute__((ext_vector_type(4)));

#define MFMA(a, b, c) __builtin_amdgcn_mfma_f32_16x16x32_bf16((a), (b), (c), 0, 0, 0)
// gfx9 s_waitcnt encodings: [3:0]=vmcnt, [6:4]=expcnt(7=nowait), [11:8]=lgkm(0xF=nowait)
#define DRAIN_VMCNT()  __builtin_amdgcn_s_waitcnt(0x0F70)   // vmcnt(0)
#define WAIT_VMCNT_2() __builtin_amdgcn_s_waitcnt(0x0F72)   // vmcnt(2): keep newest stage in flight

constexpr int Bc  = 8;
constexpr int D   = 256;
constexpr int TC  = 2048;
constexpr int TE  = 2048;
constexpr int TGT = 256;
constexpr int XR  = 256;            // xcat row stride (content half only)
constexpr int NBT = Bc * TC;        // 16384 rows

// exp(x/16) == exp2(x * log2(e)/16)
#define EXP_C 0.09016844005556021f

// async global->LDS, 16B per lane; LDS dst = base + lane*16 (wave-uniform base),
// global source address is PER-LANE (m173 pattern: pre-swizzle the source).
__device__ __forceinline__ void gl_lds16(const __bf16* g, __bf16* l) {
  __builtin_amdgcn_global_load_lds(
      (const __attribute__((address_space(1))) void*)g,
      (__attribute__((address_space(3))) void*)l, 16, 0, 0);
}

// ---- fused prep: content transpose + emotion transpose/cast + weight repack ----
// grid (TC/64 + 1, 8, Bc):
//   x < 32, y < 4 : content fp32 [B][D][TC] -> xcat bf16 [B][TC][256]
//   x < 32, y >= 4: emotion fp32 [B][D][TE] -> e_t bf16 [B][TE][256]
//                   + e_ds2 bf16 [B][64 s-tiles][256 d][32 s]  (4KB-contig chunks)
//   x == 32       : conv weight fp32 [256][512][3] -> Wk bf16 [3][256][512]
__global__ void k_prep_all(const float* __restrict__ content,
                           const float* __restrict__ emotion,
                           __bf16* __restrict__ xcat,
                           __bf16* __restrict__ e_t, __bf16* __restrict__ e_ds2,
                           const float* __restrict__ w, __bf16* __restrict__ Wk) {
  __shared__ __bf16 tile[64][68];
  const int tid = threadIdx.x;

  if (blockIdx.x == TC / 64) {       // ---- weight repack: 64 blocks x 2048 idx ----
    const int base = (blockIdx.y * Bc + blockIdx.z) * 2048;
#pragma unroll
    for (int j = 0; j < 8; ++j) {
      const int idx = base + j * 256 + tid;   // o*512 + i
      const int o = idx >> 9, i = idx & 511;
#pragma unroll
      for (int k = 0; k < 3; ++k)
        Wk[k * (TGT * 512) + idx] = (__bf16)w[(size_t)o * 1536 + i * 3 + k];
    }
    return;
  }

  const bool isC = blockIdx.y < 4;
  const int b  = blockIdx.z;
  const int t0 = blockIdx.x * 64;
  const int d0 = (blockIdx.y & 3) * 64;
  const int c4 = (tid & 15) * 4;
  const int r0 = tid >> 4;          // 0..15
  const float* sp = (isC ? content : emotion) + ((size_t)b * D + d0) * 2048 + t0;
#pragma unroll
  for (int i = 0; i < 4; ++i) {
    const int r = r0 + 16 * i;
    const float4 v = *(const float4*)(sp + (size_t)r * 2048 + c4);
    bf16x4 pv;
    pv[0] = (__bf16)v.x; pv[1] = (__bf16)v.y; pv[2] = (__bf16)v.z; pv[3] = (__bf16)v.w;
    *(bf16x4*)&tile[r][c4] = pv;
  }
  __syncthreads();

  // tile[d][t] -> transposed dst rows t, 8 d per lane, 16B stores (stride 256)
  __bf16* dp = (isC ? xcat + ((size_t)b * TC + t0) * XR
                    : e_t + ((size_t)b * TE + t0) * D) + d0;
#pragma unroll
  for (int i = 0; i < 2; ++i) {
    const int idx = tid + 256 * i;  // 0..511
    const int r   = idx >> 3;       // output row (t-local) 0..63
    const int c8  = (idx & 7) * 8;  // output col block (d-local)
    bf16x8 v;
#pragma unroll
    for (int j = 0; j < 8; ++j) v[j] = tile[c8 + j][r];
    *(bf16x8*)(dp + (size_t)r * 256 + c8) = v;
  }

  // e_ds2: row-major LDS reads (2x b64), fully-contiguous 4KB global chunks
  if (!isC) {
    const int row = tid >> 2, sc = tid & 3;   // d-local row, 16B chunk in 32-s
#pragma unroll
    for (int h = 0; h < 2; ++h) {
      bf16x4 lo = *(const bf16x4*)&tile[row][h * 32 + sc * 8];
      bf16x4 hi = *(const bf16x4*)&tile[row][h * 32 + sc * 8 + 4];
      bf16x8 v;
      v[0] = lo[0]; v[1] = lo[1]; v[2] = lo[2]; v[3] = lo[3];
      v[4] = hi[0]; v[5] = hi[1]; v[6] = hi[2]; v[7] = hi[3];
      __bf16* qp = e_ds2 +
          ((((size_t)b * 64 + (t0 >> 5) + h) * 256 + d0 + row) << 5) + sc * 8;
      *(bf16x8*)qp = v;
    }
  }
}

// ---- flash attention: 128 t x 4 waves (Tw=32), z=4 s-split, dbuf shared tiles ----
// XCD-pinned: b = blockIdx.x & 7 -> all 64 blocks of one batch on ONE XCD; per-XCD
// L2 working set ~3MB fits 4MB L2 (R3: FETCH 72.9 -> 14.4 MB). UNCHANGED from R3.
__global__ __launch_bounds__(256, 2) void k_attn(const __bf16* __restrict__ xcat,
                                                 const __bf16* __restrict__ e_t,
                                                 const __bf16* __restrict__ e_ds2,
                                                 __bf16* __restrict__ Op,
                                                 float* __restrict__ Lp) {
  __shared__ __align__(16) __bf16 sEt[2][8192];   // [buf]: row ss, chunk cs -> c=cs^(ss&7)
  __shared__ __align__(16) __bf16 sEs[2][8192];   // [buf]: row dd, slot ps -> p=ps^((dd>>2)&3)
  __shared__ __align__(16) __bf16 sP[4][2][640];  // per-wave P transpose, stride 40

  const int tid  = threadIdx.x;
  const int lane = tid & 63;
  const int w    = tid >> 6;        // 0..3 -> 32-t group
  const int q    = lane >> 4;
  const int tl   = lane & 15;
  const int b    = blockIdx.x & 7;                          // XCD-pinned batch
  const int xt   = (blockIdx.x >> 3) | (blockIdx.y << 1);   // logical t-block 0..15
  const int z    = blockIdx.z;      // s-quarter
  const int tbase = xt * 128 + w * 32;

  const __bf16* etb  = e_t  + (size_t)b * TE * D;     // [TE][D]
  const __bf16* esb2 = e_ds2 + (size_t)b * 64 * 8192; // [64 tiles][8192]

  // loop-invariant query fragments (B-operand of phase 1), 2 t-tiles
  bf16x8 cB[2][8];
#pragma unroll
  for (int tt = 0; tt < 2; ++tt) {
    const __bf16* crow = xcat + ((size_t)(b * TC) + tbase + tt * 16 + tl) * XR + q * 8;
#pragma unroll
    for (int ks = 0; ks < 8; ++ks) cB[tt][ks] = *(const bf16x8*)(crow + ks * 32);
  }

  // per-lane swizzled staging offsets; each wave stages 1/4 of each tile kind
  unsigned offEt[4], offEs[4];
#pragma unroll
  for (int c = 0; c < 4; ++c) {
    const int id = (w * 4 + c) * 64 + lane;        // 0..1023
    const int ss = id >> 5, cs = id & 31;
    offEt[c] = ss * D + (cs ^ (ss & 7)) * 8;       // row-contig global, swizzled chunk
    const int dd = id >> 2, ps = id & 3;
    offEs[c] = dd * 32 + (ps ^ ((dd >> 2) & 3)) * 8;  // tile-local, contiguous tile
  }

  f32x4 accO[2][16];
#pragma unroll
  for (int tt = 0; tt < 2; ++tt)
#pragma unroll
    for (int dt = 0; dt < 16; ++dt) accO[tt][dt] = (f32x4){0.f, 0.f, 0.f, 0.f};
  float lacc[2] = {0.f, 0.f};

  const int sbase = z * (TE / 4);
  const int sw3 = (tl >> 2) & 3;    // sEs read swizzle term

  auto stage = [&](int buf, int s0) {
    const __bf16* et = etb + (size_t)s0 * D;
    const __bf16* es = esb2 + ((size_t)(s0 >> 5)) * 8192;
#pragma unroll
    for (int c = 0; c < 4; ++c) {
      gl_lds16(et + offEt[c], &sEt[buf][(w * 4 + c) * 512]);
      gl_lds16(es + offEs[c], &sEs[buf][(w * 4 + c) * 512]);
    }
  };

  stage(0, sbase);
  DRAIN_VMCNT();
  __syncthreads();

  int cur = 0;
  for (int k = 0; k < TE / 128; ++k) {   // 16 steps of 32 s
    if (k < TE / 128 - 1) stage(cur ^ 1, sbase + (k + 1) * 32);  // prefetch, in flight

    // ---- phase 1: S^T for 32 s x 32 t ----
    f32x4 aS[2][2];
#pragma unroll
    for (int i = 0; i < 2; ++i)
#pragma unroll
      for (int j = 0; j < 2; ++j) aS[i][j] = (f32x4){0.f, 0.f, 0.f, 0.f};
    const __bf16* pe = &sEt[cur][0];
#pragma unroll
    for (int ks = 0; ks < 8; ++ks) {
      const int ch = (ks * 4 + q) ^ (tl & 7);
      bf16x8 a0 = *(const bf16x8*)(pe + (tl * 32 + ch) * 8);
      bf16x8 a1 = *(const bf16x8*)(pe + ((16 + tl) * 32 + ch) * 8);
      aS[0][0] = MFMA(a0, cB[0][ks], aS[0][0]);
      aS[0][1] = MFMA(a0, cB[1][ks], aS[0][1]);
      aS[1][0] = MFMA(a1, cB[0][ks], aS[1][0]);
      aS[1][1] = MFMA(a1, cB[1][ks], aS[1][1]);
    }

    // ---- exp + pack bf16, C-layout -> per-wave LDS transpose ----
#pragma unroll
    for (int tt = 0; tt < 2; ++tt) {
      bf16x4 w0, w1;
#pragma unroll
      for (int r = 0; r < 4; ++r) {
        float e0 = exp2f(aS[0][tt][r] * EXP_C);
        float e1 = exp2f(aS[1][tt][r] * EXP_C);
        lacc[tt] += e0 + e1;
        w0[r] = (__bf16)e0;
        w1[r] = (__bf16)e1;
      }
      __bf16* pw = &sP[w][tt][tl * 40 + q * 4];
      *(bf16x4*)pw = w0;          // P[s=q*4+r][t=tl]
      *(bf16x4*)(pw + 16) = w1;   // P[s=16+q*4+r][t=tl]
    }
    bf16x8 pB0 = *(const bf16x8*)(&sP[w][0][tl * 40 + q * 8]);
    bf16x8 pB1 = *(const bf16x8*)(&sP[w][1][tl * 40 + q * 8]);

    // ---- phase 2: O^T accumulate, 16 d-tiles, A-frag shared by both t-tiles ----
    const __bf16* ps = &sEs[cur][0];
#pragma unroll
    for (int dt = 0; dt < 16; ++dt) {
      bf16x8 a = *(const bf16x8*)(ps + ((dt * 16 + tl) * 4 + (q ^ sw3)) * 8);
      accO[0][dt] = MFMA(a, pB0, accO[0][dt]);
      accO[1][dt] = MFMA(a, pB1, accO[1][dt]);
    }

    DRAIN_VMCNT();     // prefetch (issued before compute) must have landed
    __syncthreads();   // + all waves done reading tile k before overwrite
    cur ^= 1;
  }

  // ---- per-wave epilogue: no cross-wave merge (wave owns its 32 t) ----
#pragma unroll
  for (int tt = 0; tt < 2; ++tt) {
    float v = lacc[tt];
    v += __shfl_xor(v, 16, 64);
    v += __shfl_xor(v, 32, 64);
    const size_t row = (size_t)z * NBT + b * TC + tbase + tt * 16 + tl;
    if (q == 0) Lp[row] = v;
    __bf16* orow = Op + row * D + q * 4;
#pragma unroll
    for (int dt = 0; dt < 16; ++dt) {
      bf16x4 o;
#pragma unroll
      for (int r = 0; r < 4; ++r) o[r] = (__bf16)accO[tt][dt][r];
      *(bf16x4*)(orow + dt * 16) = o;
    }
  }
}

// ---- conv1d as LDS-staged 3-tap GEMM, z-combine fused. REBUILT this round ----
// Tt=64: halves per-block weight re-reads (402->201 MB of L2 flow). 512 thr =
// 8 waves (4 o-groups x 2 t-halves), grid 256 = 1 block/CU (XCD-pinned b = x&7).
// Weight pipeline: sW[3] buffers, 2 stages in flight, counted vmcnt(2) + RAW
// s_barrier (never vmcnt(0) in-loop -- __syncthreads would force a full drain).
__global__ __launch_bounds__(512, 2) void k_conv(const __bf16* __restrict__ xcat,
                                                 const __bf16* __restrict__ Op,
                                                 const float* __restrict__ Lp,
                                                 const __bf16* __restrict__ Wk,
                                                 const float* __restrict__ bias,
                                                 float* __restrict__ out) {
  __shared__ __align__(16) __bf16 sXA[66 * 256];   // content half, rows t0-1..t0+64
  __shared__ __align__(16) __bf16 sXB[66 * 256];   // normalized attn half
  __shared__ __align__(16) __bf16 sW[3][8192];     // row o, slot ps -> p=ps^((o>>2)&3)
  const int tid  = threadIdx.x;
  const int lane = tid & 63;
  const int wv   = tid >> 6;        // 0..7
  const int wo   = wv & 3;          // o-group (64 o)
  const int wt   = wv >> 2;         // t-half (32 t)
  const int q    = lane >> 4;
  const int tl   = lane & 15;
  const int b    = blockIdx.x & 7;  // XCD-pinned batch
  const int t0   = (blockIdx.x >> 3) * 64;
  const int o0   = wo * 64;
  const int sw3  = (tl >> 2) & 3;
  const int rh   = lane >> 5;       // row-within-pair for staging
  const int l5   = lane & 31;

  // ---- plane A: DMA 2 rows per instruction, swizzled global source ----
  const __bf16* xb = xcat + (size_t)b * TC * XR;
  for (int i = wv; i < 33; i += 8) {
    const int rl = 2 * i + rh;                   // local row 0..65
    int gr = t0 - 1 + rl;
    gr = gr < 0 ? 0 : (gr > TC - 1 ? TC - 1 : gr);
    const int cs = l5 ^ (rl & 7);                // 16B-chunk index, pre-swizzled
    gl_lds16(xb + (size_t)gr * XR + cs * 8, &sXA[i * 512]);
  }

  // ---- weight staging offsets (swizzled, 64B-coalesced per o-row) ----
  unsigned offW[2];
#pragma unroll
  for (int c = 0; c < 2; ++c) {
    const int id = (wv * 2 + c) * 64 + lane;     // 0..1023
    const int o = id >> 2, ps = id & 3;
    offW[c] = o * 512 + (ps ^ ((o >> 2) & 3)) * 8;
  }
  auto stageW = [&](int buf, int s) {
    const int kk = s >> 4, is = s & 15;
    const __bf16* wb = Wk + (size_t)kk * TGT * 512 + is * 32;
#pragma unroll
    for (int c = 0; c < 2; ++c)
      gl_lds16(wb + offW[c], &sW[buf][(wv * 2 + c) * 512]);
  };
  stageW(0, 0);
  stageW(1, 1);

  // ---- plane B: combine 4 z-partials + normalize, swizzled ds_write ----
  for (int i = wv; i < 33; i += 8) {
    const int rl = 2 * i + rh;
    int gr = t0 - 1 + rl;
    gr = gr < 0 ? 0 : (gr > TC - 1 ? TC - 1 : gr);
    const size_t row = (size_t)b * TC + gr;
    const float inv = 1.0f /
        (Lp[row] + Lp[NBT + row] + Lp[2 * NBT + row] + Lp[3 * NBT + row]);
    float a8[8] = {0.f, 0.f, 0.f, 0.f, 0.f, 0.f, 0.f, 0.f};
#pragma unroll
    for (int zz = 0; zz < 4; ++zz) {
      bf16x8 a = *(const bf16x8*)(Op + ((size_t)zz * NBT + row) * D + l5 * 8);
#pragma unroll
      for (int r = 0; r < 8; ++r) a8[r] += (float)a[r];
    }
    bf16x8 o;
#pragma unroll
    for (int r = 0; r < 8; ++r) o[r] = (__bf16)(a8[r] * inv);
    *(bf16x8*)((char*)&sXB[rl * 256] + ((l5 * 16) ^ ((rl & 7) << 4))) = o;
  }

  DRAIN_VMCNT();                    // prologue: full drain is fine (once)
  __syncthreads();

  // halo rows: replace clamped duplicates with zeros (conv zero-padding)
  if (t0 == 0 && tid < 256) { sXA[tid] = (__bf16)0.f; sXB[tid] = (__bf16)0.f; }
  if (t0 + 64 == TC && tid < 256) {
    sXA[65 * 256 + tid] = (__bf16)0.f; sXB[65 * 256 + tid] = (__bf16)0.f;
  }
  __syncthreads();

  f32x4 acc[4][2];
#pragma unroll
  for (int mt = 0; mt < 4; ++mt) {
#pragma unroll
    for (int r = 0; r < 4; ++r) {
      const float bv = bias[o0 + mt * 16 + q * 4 + r];
#pragma unroll
      for (int nt = 0; nt < 2; ++nt) acc[mt][nt][r] = bv;
    }
  }

  int cur = 0;                      // buf index = s % 3
  for (int s = 0; s < 48; ++s) {
    if (s < 46) stageW((cur + 2) % 3, s + 2);    // keep 2 stages in flight
    const int kk = s >> 4, is = s & 15;
    const __bf16* pl = (is & 8) ? sXB : sXA;     // ch 256:512 -> plane B
    const int cbyte = (is & 7) * 64 + q * 16;    // byte col base within plane
    bf16x8 bfr[2];
#pragma unroll
    for (int nt = 0; nt < 2; ++nt) {
      const int t = wt * 32 + nt * 16 + tl + kk;
      bfr[nt] = *(const bf16x8*)((const char*)pl + t * 512 + (cbyte ^ ((t & 7) << 4)));
    }
#pragma unroll
    for (int mt = 0; mt < 4; ++mt) {
      const int o = o0 + mt * 16 + tl;
      bf16x8 af = *(const bf16x8*)(&sW[cur][(o * 4 + (q ^ sw3)) * 8]);
#pragma unroll
      for (int nt = 0; nt < 2; ++nt) acc[mt][nt] = MFMA(af, bfr[nt], acc[mt][nt]);
    }
    // counted wait: next buffer's stage (issued last iter) landed; newest stays
    // in flight. Raw s_barrier -- __syncthreads would emit vmcnt(0) and kill it.
    if (s < 46) WAIT_VMCNT_2(); else DRAIN_VMCNT();
    __builtin_amdgcn_s_barrier();
    __builtin_amdgcn_sched_barrier(0);           // no ds_read hoisting across barrier
    cur = cur == 2 ? 0 : cur + 1;
  }

#pragma unroll
  for (int mt = 0; mt < 4; ++mt) {
#pragma unroll
    for (int nt = 0; nt < 2; ++nt) {
#pragma unroll
      for (int r = 0; r < 4; ++r) {
        const int o = o0 + mt * 16 + q * 4 + r;
        const int t = t0 + wt * 32 + nt * 16 + tl;
        out[((size_t)b * TGT + o) * TC + t] = acc[mt][nt][r];
      }
    }
  }
}

extern "C" void kernel_launch(void* const* d_in, const int* in_sizes, int n_in,
                              void* d_out, int out_size, void* d_ws, size_t ws_size,
                              hipStream_t stream) {
  (void)in_sizes; (void)n_in; (void)out_size; (void)ws_size;
  const float* content = (const float*)d_in[0];  // fp32 [B][256][2048]
  const float* emotion = (const float*)d_in[1];  // fp32 [B][256][2048]
  const float* conv_w  = (const float*)d_in[2];  // fp32 [256][512][3]
  const float* conv_b  = (const float*)d_in[3];  // fp32 [256]
  float* out = (float*)d_out;                    // fp32 [B][256][2048]

  char* ws = (char*)d_ws;
  __bf16* xcat = (__bf16*)ws;                          //  8,388,608 B
  __bf16* Wk   = (__bf16*)(ws + 8388608);              //    786,432 B
  __bf16* Op   = (__bf16*)(ws + 9437184);              // 33,554,432 B (4 z-partials)
  float*  Lp   = (float*)(ws + 42991616);              //    262,144 B (total 43.3 MB)
  // e_t + e_ds2 live in d_out (8,388,608 B each); consumed before k_conv writes out.
  __bf16* e_t   = (__bf16*)d_out;                      // bf16 [B][TE][D]
  __bf16* e_ds2 = (__bf16*)((char*)d_out + 8388608);   // bf16 [B][64][256][32]

  k_prep_all<<<dim3(TC / 64 + 1, 8, Bc), 256, 0, stream>>>(
      content, emotion, xcat, e_t, e_ds2, conv_w, Wk);
  k_attn<<<dim3(TC / 128, Bc, 4), 256, 0, stream>>>(xcat, e_t, e_ds2, Op, Lp);
  k_conv<<<dim3((TC / 64) * Bc), 512, 0, stream>>>(xcat, Op, Lp, Wk, conv_b, out);
}

// Round 5
// 171.947 us; speedup vs baseline: 1.0047x; 1.0047x over previous
//
#include <hip/hip_runtime.h>

typedef __bf16 bf16x8 __attribute__((ext_vector_type(8)));
typedef __bf16 bf16x4 __attribute__((ext_vector_type(4)));
typedef float  f32x4  __attribute__((ext_vector_type(4)));

#define MFMA(a, b, c) __builtin_amdgcn_mfma_f32_16x16x32_bf16((a), (b), (c), 0, 0, 0)
// gfx9 s_waitcnt encodings: [3:0]=vmcnt, [6:4]=expcnt(7=nowait), [11:8]=lgkm(0xF=nowait)
#define DRAIN_VMCNT()  __builtin_amdgcn_s_waitcnt(0x0F70)   // vmcnt(0)
#define WAIT_VMCNT_2() __builtin_amdgcn_s_waitcnt(0x0F72)   // vmcnt(2)

constexpr int Bc  = 8;
constexpr int D   = 256;
constexpr int TC  = 2048;
constexpr int TE  = 2048;
constexpr int TGT = 256;
constexpr int XR  = 256;            // xcat row stride (content half only)

// exp(x/16) == exp2(x * log2(e)/16)
#define EXP_C 0.09016844005556021f

// async global->LDS, 16B per lane; LDS dst = base + lane*16 (wave-uniform base),
// global source address is PER-LANE (m173 pattern: pre-swizzle the source).
__device__ __forceinline__ void gl_lds16(const __bf16* g, __bf16* l) {
  __builtin_amdgcn_global_load_lds(
      (const __attribute__((address_space(1))) void*)g,
      (__attribute__((address_space(3))) void*)l, 16, 0, 0);
}

// ---- fused prep: content transpose + emotion transpose/cast + weight repack ----
// XCD-PINNED grid (Bc, TC/64 + 1, 8): linear id = x + 8*(y + 33*z) -> XCD = x = b.
// All of batch b's outputs (xcat, e_t, e_ds2) are produced on XCD b, matching the
// XCD-pinned consumers (k_attn, k_conv) -> same-L2 handoff.
//   y < 32, z < 4 : content fp32 [B][D][TC] -> xcat bf16 [B][TC][256]
//   y < 32, z >= 4: emotion fp32 [B][D][TE] -> e_t bf16 [B][TE][256]
//                   + e_ds2 bf16 [B][64 s-tiles][256 d][32 s]  (4KB-contig chunks)
//   y == 32       : conv weight fp32 [256][512][3] -> Wk bf16 [3][256][512]
__global__ void k_prep_all(const float* __restrict__ content,
                           const float* __restrict__ emotion,
                           __bf16* __restrict__ xcat,
                           __bf16* __restrict__ e_t, __bf16* __restrict__ e_ds2,
                           const float* __restrict__ w, __bf16* __restrict__ Wk) {
  __shared__ __bf16 tile[64][68];
  const int tid = threadIdx.x;

  if (blockIdx.y == TC / 64) {       // ---- weight repack: 64 blocks x 2048 idx ----
    const int base = (blockIdx.z * 8 + blockIdx.x) * 2048;
#pragma unroll
    for (int j = 0; j < 8; ++j) {
      const int idx = base + j * 256 + tid;   // o*512 + i
      const int o = idx >> 9, i = idx & 511;
#pragma unroll
      for (int k = 0; k < 3; ++k)
        Wk[k * (TGT * 512) + idx] = (__bf16)w[(size_t)o * 1536 + i * 3 + k];
    }
    return;
  }

  const int b   = blockIdx.x;        // == XCD id
  const int t0  = blockIdx.y * 64;
  const int sec = blockIdx.z;
  const bool isC = sec < 4;
  const int d0 = (sec & 3) * 64;
  const int c4 = (tid & 15) * 4;
  const int r0 = tid >> 4;          // 0..15
  const float* sp = (isC ? content : emotion) + ((size_t)b * D + d0) * 2048 + t0;
#pragma unroll
  for (int i = 0; i < 4; ++i) {
    const int r = r0 + 16 * i;
    const float4 v = *(const float4*)(sp + (size_t)r * 2048 + c4);
    bf16x4 pv;
    pv[0] = (__bf16)v.x; pv[1] = (__bf16)v.y; pv[2] = (__bf16)v.z; pv[3] = (__bf16)v.w;
    *(bf16x4*)&tile[r][c4] = pv;
  }
  __syncthreads();

  // tile[d][t] -> transposed dst rows t, 8 d per lane, 16B stores (stride 256)
  __bf16* dp = (isC ? xcat + ((size_t)b * TC + t0) * XR
                    : e_t + ((size_t)b * TE + t0) * D) + d0;
#pragma unroll
  for (int i = 0; i < 2; ++i) {
    const int idx = tid + 256 * i;  // 0..511
    const int r   = idx >> 3;       // output row (t-local) 0..63
    const int c8  = (idx & 7) * 8;  // output col block (d-local)
    bf16x8 v;
#pragma unroll
    for (int j = 0; j < 8; ++j) v[j] = tile[c8 + j][r];
    *(bf16x8*)(dp + (size_t)r * 256 + c8) = v;
  }

  // e_ds2: row-major LDS reads (2x b64), fully-contiguous 4KB global chunks
  if (!isC) {
    const int row = tid >> 2, sc = tid & 3;   // d-local row, 16B chunk in 32-s
#pragma unroll
    for (int h = 0; h < 2; ++h) {
      bf16x4 lo = *(const bf16x4*)&tile[row][h * 32 + sc * 8];
      bf16x4 hi = *(const bf16x4*)&tile[row][h * 32 + sc * 8 + 4];
      bf16x8 v;
      v[0] = lo[0]; v[1] = lo[1]; v[2] = lo[2]; v[3] = lo[3];
      v[4] = hi[0]; v[5] = hi[1]; v[6] = hi[2]; v[7] = hi[3];
      __bf16* qp = e_ds2 +
          ((((size_t)b * 64 + (t0 >> 5) + h) * 256 + d0 + row) << 5) + sc * 8;
      *(bf16x8*)qp = v;
    }
  }
}

// ---- flash attention: 128 t x 4 waves (Tw=32), z=4 s-split, dbuf shared tiles ----
// XCD-pinned: b = blockIdx.x & 7 (R3: FETCH 72.9 -> 14.4 MB). Core UNCHANGED.
// Op/Lp now z-INTERLEAVED: Op[row][z][256], Lp[row][4] (conv reads contiguous).
__global__ __launch_bounds__(256, 2) void k_attn(const __bf16* __restrict__ xcat,
                                                 const __bf16* __restrict__ e_t,
                                                 const __bf16* __restrict__ e_ds2,
                                                 __bf16* __restrict__ Op,
                                                 float* __restrict__ Lp) {
  __shared__ __align__(16) __bf16 sEt[2][8192];   // [buf]: row ss, chunk cs -> c=cs^(ss&7)
  __shared__ __align__(16) __bf16 sEs[2][8192];   // [buf]: row dd, slot ps -> p=ps^((dd>>2)&3)
  __shared__ __align__(16) __bf16 sP[4][2][640];  // per-wave P transpose, stride 40

  const int tid  = threadIdx.x;
  const int lane = tid & 63;
  const int w    = tid >> 6;        // 0..3 -> 32-t group
  const int q    = lane >> 4;
  const int tl   = lane & 15;
  const int b    = blockIdx.x & 7;                          // XCD-pinned batch
  const int xt   = (blockIdx.x >> 3) | (blockIdx.y << 1);   // logical t-block 0..15
  const int z    = blockIdx.z;      // s-quarter
  const int tbase = xt * 128 + w * 32;

  const __bf16* etb  = e_t  + (size_t)b * TE * D;     // [TE][D]
  const __bf16* esb2 = e_ds2 + (size_t)b * 64 * 8192; // [64 tiles][8192]

  // loop-invariant query fragments (B-operand of phase 1), 2 t-tiles
  bf16x8 cB[2][8];
#pragma unroll
  for (int tt = 0; tt < 2; ++tt) {
    const __bf16* crow = xcat + ((size_t)(b * TC) + tbase + tt * 16 + tl) * XR + q * 8;
#pragma unroll
    for (int ks = 0; ks < 8; ++ks) cB[tt][ks] = *(const bf16x8*)(crow + ks * 32);
  }

  // per-lane swizzled staging offsets; each wave stages 1/4 of each tile kind
  unsigned offEt[4], offEs[4];
#pragma unroll
  for (int c = 0; c < 4; ++c) {
    const int id = (w * 4 + c) * 64 + lane;        // 0..1023
    const int ss = id >> 5, cs = id & 31;
    offEt[c] = ss * D + (cs ^ (ss & 7)) * 8;       // row-contig global, swizzled chunk
    const int dd = id >> 2, ps = id & 3;
    offEs[c] = dd * 32 + (ps ^ ((dd >> 2) & 3)) * 8;  // tile-local, contiguous tile
  }

  f32x4 accO[2][16];
#pragma unroll
  for (int tt = 0; tt < 2; ++tt)
#pragma unroll
    for (int dt = 0; dt < 16; ++dt) accO[tt][dt] = (f32x4){0.f, 0.f, 0.f, 0.f};
  float lacc[2] = {0.f, 0.f};

  const int sbase = z * (TE / 4);
  const int sw3 = (tl >> 2) & 3;    // sEs read swizzle term

  auto stage = [&](int buf, int s0) {
    const __bf16* et = etb + (size_t)s0 * D;
    const __bf16* es = esb2 + ((size_t)(s0 >> 5)) * 8192;
#pragma unroll
    for (int c = 0; c < 4; ++c) {
      gl_lds16(et + offEt[c], &sEt[buf][(w * 4 + c) * 512]);
      gl_lds16(es + offEs[c], &sEs[buf][(w * 4 + c) * 512]);
    }
  };

  stage(0, sbase);
  DRAIN_VMCNT();
  __syncthreads();

  int cur = 0;
  for (int k = 0; k < TE / 128; ++k) {   // 16 steps of 32 s
    if (k < TE / 128 - 1) stage(cur ^ 1, sbase + (k + 1) * 32);  // prefetch, in flight

    // ---- phase 1: S^T for 32 s x 32 t ----
    f32x4 aS[2][2];
#pragma unroll
    for (int i = 0; i < 2; ++i)
#pragma unroll
      for (int j = 0; j < 2; ++j) aS[i][j] = (f32x4){0.f, 0.f, 0.f, 0.f};
    const __bf16* pe = &sEt[cur][0];
#pragma unroll
    for (int ks = 0; ks < 8; ++ks) {
      const int ch = (ks * 4 + q) ^ (tl & 7);
      bf16x8 a0 = *(const bf16x8*)(pe + (tl * 32 + ch) * 8);
      bf16x8 a1 = *(const bf16x8*)(pe + ((16 + tl) * 32 + ch) * 8);
      aS[0][0] = MFMA(a0, cB[0][ks], aS[0][0]);
      aS[0][1] = MFMA(a0, cB[1][ks], aS[0][1]);
      aS[1][0] = MFMA(a1, cB[0][ks], aS[1][0]);
      aS[1][1] = MFMA(a1, cB[1][ks], aS[1][1]);
    }

    // ---- exp + pack bf16, C-layout -> per-wave LDS transpose ----
#pragma unroll
    for (int tt = 0; tt < 2; ++tt) {
      bf16x4 w0, w1;
#pragma unroll
      for (int r = 0; r < 4; ++r) {
        float e0 = exp2f(aS[0][tt][r] * EXP_C);
        float e1 = exp2f(aS[1][tt][r] * EXP_C);
        lacc[tt] += e0 + e1;
        w0[r] = (__bf16)e0;
        w1[r] = (__bf16)e1;
      }
      __bf16* pw = &sP[w][tt][tl * 40 + q * 4];
      *(bf16x4*)pw = w0;          // P[s=q*4+r][t=tl]
      *(bf16x4*)(pw + 16) = w1;   // P[s=16+q*4+r][t=tl]
    }
    bf16x8 pB0 = *(const bf16x8*)(&sP[w][0][tl * 40 + q * 8]);
    bf16x8 pB1 = *(const bf16x8*)(&sP[w][1][tl * 40 + q * 8]);

    // ---- phase 2: O^T accumulate, 16 d-tiles, A-frag shared by both t-tiles ----
    const __bf16* ps = &sEs[cur][0];
#pragma unroll
    for (int dt = 0; dt < 16; ++dt) {
      bf16x8 a = *(const bf16x8*)(ps + ((dt * 16 + tl) * 4 + (q ^ sw3)) * 8);
      accO[0][dt] = MFMA(a, pB0, accO[0][dt]);
      accO[1][dt] = MFMA(a, pB1, accO[1][dt]);
    }

    DRAIN_VMCNT();     // prefetch (issued before compute) must have landed
    __syncthreads();   // + all waves done reading tile k before overwrite
    cur ^= 1;
  }

  // ---- per-wave epilogue: z-interleaved partial O/L ----
#pragma unroll
  for (int tt = 0; tt < 2; ++tt) {
    float v = lacc[tt];
    v += __shfl_xor(v, 16, 64);
    v += __shfl_xor(v, 32, 64);
    const size_t rowl = (size_t)b * TC + tbase + tt * 16 + tl;
    if (q == 0) Lp[rowl * 4 + z] = v;
    __bf16* orow = Op + (rowl * 4 + z) * D + q * 4;
#pragma unroll
    for (int dt = 0; dt < 16; ++dt) {
      bf16x4 o;
#pragma unroll
      for (int r = 0; r < 4; ++r) o[r] = (__bf16)accO[tt][dt][r];
      *(bf16x4*)(orow + dt * 16) = o;
    }
  }
}

// ---- conv1d as LDS-staged 3-tap GEMM, z-combine fused (Tt=64, R4 pipeline) ----
// Op/Lp z-interleaved: per row the combine reads one contiguous 2KB block + a
// single float4 of L (was 4x 512B strided 8.4MB apart + 4 scalar loads).
__global__ __launch_bounds__(512, 2) void k_conv(const __bf16* __restrict__ xcat,
                                                 const __bf16* __restrict__ Op,
                                                 const float* __restrict__ Lp,
                                                 const __bf16* __restrict__ Wk,
                                                 const float* __restrict__ bias,
                                                 float* __restrict__ out) {
  __shared__ __align__(16) __bf16 sXA[66 * 256];   // content half, rows t0-1..t0+64
  __shared__ __align__(16) __bf16 sXB[66 * 256];   // normalized attn half
  __shared__ __align__(16) __bf16 sW[3][8192];     // row o, slot ps -> p=ps^((o>>2)&3)
  const int tid  = threadIdx.x;
  const int lane = tid & 63;
  const int wv   = tid >> 6;        // 0..7
  const int wo   = wv & 3;          // o-group (64 o)
  const int wt   = wv >> 2;         // t-half (32 t)
  const int q    = lane >> 4;
  const int tl   = lane & 15;
  const int b    = blockIdx.x & 7;  // XCD-pinned batch
  const int t0   = (blockIdx.x >> 3) * 64;
  const int o0   = wo * 64;
  const int sw3  = (tl >> 2) & 3;
  const int rh   = lane >> 5;       // row-within-pair for staging
  const int l5   = lane & 31;

  // ---- plane A: DMA 2 rows per instruction, swizzled global source ----
  const __bf16* xb = xcat + (size_t)b * TC * XR;
  for (int i = wv; i < 33; i += 8) {
    const int rl = 2 * i + rh;                   // local row 0..65
    int gr = t0 - 1 + rl;
    gr = gr < 0 ? 0 : (gr > TC - 1 ? TC - 1 : gr);
    const int cs = l5 ^ (rl & 7);                // 16B-chunk index, pre-swizzled
    gl_lds16(xb + (size_t)gr * XR + cs * 8, &sXA[i * 512]);
  }

  // ---- weight staging offsets (swizzled, 64B-coalesced per o-row) ----
  unsigned offW[2];
#pragma unroll
  for (int c = 0; c < 2; ++c) {
    const int id = (wv * 2 + c) * 64 + lane;     // 0..1023
    const int o = id >> 2, ps = id & 3;
    offW[c] = o * 512 + (ps ^ ((o >> 2) & 3)) * 8;
  }
  auto stageW = [&](int buf, int s) {
    const int kk = s >> 4, is = s & 15;
    const __bf16* wb = Wk + (size_t)kk * TGT * 512 + is * 32;
#pragma unroll
    for (int c = 0; c < 2; ++c)
      gl_lds16(wb + offW[c], &sW[buf][(wv * 2 + c) * 512]);
  };
  stageW(0, 0);
  stageW(1, 1);

  // ---- plane B: combine 4 z-partials + normalize, swizzled ds_write ----
  for (int i = wv; i < 33; i += 8) {
    const int rl = 2 * i + rh;
    int gr = t0 - 1 + rl;
    gr = gr < 0 ? 0 : (gr > TC - 1 ? TC - 1 : gr);
    const size_t row = (size_t)b * TC + gr;
    const float4 lv = *(const float4*)(Lp + row * 4);
    const float inv = 1.0f / (lv.x + lv.y + lv.z + lv.w);
    float a8[8] = {0.f, 0.f, 0.f, 0.f, 0.f, 0.f, 0.f, 0.f};
#pragma unroll
    for (int zz = 0; zz < 4; ++zz) {
      bf16x8 a = *(const bf16x8*)(Op + (row * 4 + zz) * D + l5 * 8);
#pragma unroll
      for (int r = 0; r < 8; ++r) a8[r] += (float)a[r];
    }
    bf16x8 o;
#pragma unroll
    for (int r = 0; r < 8; ++r) o[r] = (__bf16)(a8[r] * inv);
    *(bf16x8*)((char*)&sXB[rl * 256] + ((l5 * 16) ^ ((rl & 7) << 4))) = o;
  }

  DRAIN_VMCNT();                    // prologue: full drain is fine (once)
  __syncthreads();

  // halo rows: replace clamped duplicates with zeros (conv zero-padding)
  if (t0 == 0 && tid < 256) { sXA[tid] = (__bf16)0.f; sXB[tid] = (__bf16)0.f; }
  if (t0 + 64 == TC && tid < 256) {
    sXA[65 * 256 + tid] = (__bf16)0.f; sXB[65 * 256 + tid] = (__bf16)0.f;
  }
  __syncthreads();

  f32x4 acc[4][2];
#pragma unroll
  for (int mt = 0; mt < 4; ++mt) {
#pragma unroll
    for (int r = 0; r < 4; ++r) {
      const float bv = bias[o0 + mt * 16 + q * 4 + r];
#pragma unroll
      for (int nt = 0; nt < 2; ++nt) acc[mt][nt][r] = bv;
    }
  }

  int cur = 0;                      // buf index = s % 3
  for (int s = 0; s < 48; ++s) {
    if (s < 46) stageW((cur + 2) % 3, s + 2);    // keep 2 stages in flight
    const int kk = s >> 4, is = s & 15;
    const __bf16* pl = (is & 8) ? sXB : sXA;     // ch 256:512 -> plane B
    const int cbyte = (is & 7) * 64 + q * 16;    // byte col base within plane
    bf16x8 bfr[2];
#pragma unroll
    for (int nt = 0; nt < 2; ++nt) {
      const int t = wt * 32 + nt * 16 + tl + kk;
      bfr[nt] = *(const bf16x8*)((const char*)pl + t * 512 + (cbyte ^ ((t & 7) << 4)));
    }
#pragma unroll
    for (int mt = 0; mt < 4; ++mt) {
      const int o = o0 + mt * 16 + tl;
      bf16x8 af = *(const bf16x8*)(&sW[cur][(o * 4 + (q ^ sw3)) * 8]);
#pragma unroll
      for (int nt = 0; nt < 2; ++nt) acc[mt][nt] = MFMA(af, bfr[nt], acc[mt][nt]);
    }
    // counted wait: next buffer's stage (issued last iter) landed; newest stays
    // in flight. Raw s_barrier -- __syncthreads would emit vmcnt(0) and kill it.
    if (s < 46) WAIT_VMCNT_2(); else DRAIN_VMCNT();
    __builtin_amdgcn_s_barrier();
    __builtin_amdgcn_sched_barrier(0);           // no ds_read hoisting across barrier
    cur = cur == 2 ? 0 : cur + 1;
  }

#pragma unroll
  for (int mt = 0; mt < 4; ++mt) {
#pragma unroll
    for (int nt = 0; nt < 2; ++nt) {
#pragma unroll
      for (int r = 0; r < 4; ++r) {
        const int o = o0 + mt * 16 + q * 4 + r;
        const int t = t0 + wt * 32 + nt * 16 + tl;
        out[((size_t)b * TGT + o) * TC + t] = acc[mt][nt][r];
      }
    }
  }
}

extern "C" void kernel_launch(void* const* d_in, const int* in_sizes, int n_in,
                              void* d_out, int out_size, void* d_ws, size_t ws_size,
                              hipStream_t stream) {
  (void)in_sizes; (void)n_in; (void)out_size; (void)ws_size;
  const float* content = (const float*)d_in[0];  // fp32 [B][256][2048]
  const float* emotion = (const float*)d_in[1];  // fp32 [B][256][2048]
  const float* conv_w  = (const float*)d_in[2];  // fp32 [256][512][3]
  const float* conv_b  = (const float*)d_in[3];  // fp32 [256]
  float* out = (float*)d_out;                    // fp32 [B][256][2048]

  char* ws = (char*)d_ws;
  __bf16* xcat = (__bf16*)ws;                          //  8,388,608 B
  __bf16* Wk   = (__bf16*)(ws + 8388608);              //    786,432 B
  __bf16* Op   = (__bf16*)(ws + 9437184);              // 33,554,432 B (z-interleaved)
  float*  Lp   = (float*)(ws + 42991616);              //    262,144 B (total 43.3 MB)
  // e_t + e_ds2 live in d_out (8,388,608 B each); consumed before k_conv writes out.
  __bf16* e_t   = (__bf16*)d_out;                      // bf16 [B][TE][D]
  __bf16* e_ds2 = (__bf16*)((char*)d_out + 8388608);   // bf16 [B][64][256][32]

  k_prep_all<<<dim3(Bc, TC / 64 + 1, 8), 256, 0, stream>>>(
      content, emotion, xcat, e_t, e_ds2, conv_w, Wk);
  k_attn<<<dim3(TC / 128, Bc, 4), 256, 0, stream>>>(xcat, e_t, e_ds2, Op, Lp);
  k_conv<<<dim3((TC / 64) * Bc), 512, 0, stream>>>(xcat, Op, Lp, Wk, conv_b, out);
}

// Round 7
// 167.241 us; speedup vs baseline: 1.0329x; 1.0281x over previous
//
#include <hip/hip_runtime.h>

typedef __bf16 bf16x8 __attribute__((ext_vector_type(8)));
typedef __bf16 bf16x4 __attribute__((ext_vector_type(4)));
typedef float  f32x4  __attribute__((ext_vector_type(4)));

#define MFMA(a, b, c) __builtin_amdgcn_mfma_f32_16x16x32_bf16((a), (b), (c), 0, 0, 0)
// gfx9 s_waitcnt encodings: [3:0]=vmcnt(low), [6:4]=expcnt(7=nowait), [11:8]=lgkm(0xF=nowait)
#define WAIT_VMCNT(n)  __builtin_amdgcn_s_waitcnt(0x0F70 | (n))
#define DRAIN_VMCNT()  __builtin_amdgcn_s_waitcnt(0x0F70)
#define WAIT_VMCNT_2() __builtin_amdgcn_s_waitcnt(0x0F72)
// raw barrier (no vmcnt(0) drain) + scheduler fence
#define BARRIER() do { __builtin_amdgcn_s_barrier(); __builtin_amdgcn_sched_barrier(0); } while (0)

constexpr int Bc  = 8;
constexpr int D   = 256;
constexpr int TC  = 2048;
constexpr int TE  = 2048;
constexpr int TGT = 256;
constexpr int XR  = 256;            // xcat row stride (content half only)

// exp(x/16) == exp2(x * log2(e)/16)
#define EXP_C 0.09016844005556021f

// async global->LDS, 16B per lane; LDS dst = base + lane*16 (wave-uniform base)
__device__ __forceinline__ void gl_lds16(const __bf16* g, __bf16* l) {
  __builtin_amdgcn_global_load_lds(
      (const __attribute__((address_space(1))) void*)g,
      (__attribute__((address_space(3))) void*)l, 16, 0, 0);
}

// hardware transpose read (verified semantics, m156/m162 reconciled):
// lane reads COLUMN ((addr&127)/8) of the row-major 4x16 bf16 tile at the
// 128B-aligned window (addr & ~127); elem j = row j (addr elem +16*j).
__device__ __forceinline__ bf16x4 tr_b64(unsigned addr) {
  bf16x4 d;
  asm volatile("ds_read_b64_tr_b16 %0, %1" : "=v"(d) : "v"(addr));
  return d;
}

// ---- fused prep: content transpose + emotion subtile-pack + weight repack ----
// XCD-PINNED grid (Bc, TC/64 + 1, 8): linear id = x + 8*(y + 33*z) -> XCD = x = b.
//   y < 32, z < 4 : content fp32 [B][D][TC] -> xcat bf16 [B][TC][256]
//   y < 32, z >= 4: emotion fp32 [B][D][TE] -> e_t2 bf16 [B][64 stile][2 sh][16 dt][16 s][16 d]
//                   (exact LDS tile image: one 16KB contiguous block per 32-s tile)
//   y == 32       : conv weight fp32 [256][512][3] -> Wk bf16 [3][256][512]
__global__ void k_prep_all(const float* __restrict__ content,
                           const float* __restrict__ emotion,
                           __bf16* __restrict__ xcat, __bf16* __restrict__ e_t2,
                           const float* __restrict__ w, __bf16* __restrict__ Wk) {
  __shared__ __bf16 tile[64][68];
  const int tid = threadIdx.x;

  if (blockIdx.y == TC / 64) {       // ---- weight repack: 64 blocks x 2048 idx ----
    const int base = (blockIdx.z * 8 + blockIdx.x) * 2048;
#pragma unroll
    for (int j = 0; j < 8; ++j) {
      const int idx = base + j * 256 + tid;   // o*512 + i
      const int o = idx >> 9, i = idx & 511;
#pragma unroll
      for (int k = 0; k < 3; ++k)
        Wk[k * (TGT * 512) + idx] = (__bf16)w[(size_t)o * 1536 + i * 3 + k];
    }
    return;
  }

  const int b   = blockIdx.x;        // == XCD id
  const int t0  = blockIdx.y * 64;
  const int sec = blockIdx.z;
  const bool isC = sec < 4;
  const int d0 = (sec & 3) * 64;
  const int c4 = (tid & 15) * 4;
  const int r0 = tid >> 4;          // 0..15
  const float* sp = (isC ? content : emotion) + ((size_t)b * D + d0) * 2048 + t0;
#pragma unroll
  for (int i = 0; i < 4; ++i) {
    const int r = r0 + 16 * i;
    const float4 v = *(const float4*)(sp + (size_t)r * 2048 + c4);
    bf16x4 pv;
    pv[0] = (__bf16)v.x; pv[1] = (__bf16)v.y; pv[2] = (__bf16)v.z; pv[3] = (__bf16)v.w;
    *(bf16x4*)&tile[r][c4] = pv;
  }
  __syncthreads();

  if (isC) {
    // tile[d][t] -> xcat rows t, 8 d per lane, 16B stores (stride 256)
    __bf16* dp = xcat + ((size_t)b * TC + t0) * XR + d0;
#pragma unroll
    for (int i = 0; i < 2; ++i) {
      const int idx = tid + 256 * i;  // 0..511
      const int r   = idx >> 3;       // t-local 0..63
      const int c8  = (idx & 7) * 8;  // d-local chunk
      bf16x8 v;
#pragma unroll
      for (int j = 0; j < 8; ++j) v[j] = tile[c8 + j][r];
      *(bf16x8*)(dp + (size_t)r * 256 + c8) = v;
    }
  } else {
    // e_t2 subtile pack: value e[s=t0+r][d=d0+dc*8+j] ->
    //   [stile][sh][dt][s&15][d&15], stile=(t0+r)>>5, sh=(r>>4)&1, dt=(d0>>4)+(dc>>1)
    __bf16* base = e_t2 + (size_t)b * TE * D + (size_t)(t0 >> 5) * 8192
                   + (size_t)(d0 >> 4) * 256;
#pragma unroll
    for (int i = 0; i < 2; ++i) {
      const int idx = tid + 256 * i;
      const int r   = idx >> 3;       // s-local 0..63
      const int dc  = idx & 7;        // d chunk of 8
      bf16x8 v;
#pragma unroll
      for (int j = 0; j < 8; ++j) v[j] = tile[dc * 8 + j][r];
      __bf16* qp = base + (r >> 5) * 8192
                   + ((((r >> 4) & 1) * 16 + (dc >> 1)) * 16 + (r & 15)) * 16
                   + (dc & 1) * 8;
      *(bf16x8*)qp = v;
    }
  }
}

// ---- flash attention: single-tile staging + tr-read PV, 3-buf counted vmcnt ----
// Per 32-s step stages ONE 16KB e_t2 tile (subtiled [sh][dt][16s][16d]).
// Phase 1 (QK^T): row-contiguous b128 reads, standard A-frag.
// Phase 2 (PV): ds_read_b64_tr_b16; lane addr = tile + dt*512B + q*128B + 8*tl
// -> window (dt, s-quad 4q..4q+3 [+16 for sh]), column d=tl; k-slot permutation
// s'={4q+j, 16+4q+j} applied IDENTICALLY to the P fragments -> dot products exact.
// Pipeline: stage(k+2) each step; end-of-step vmcnt(4) (stage k+1 landed, k+2 in
// flight) BEFORE raw s_barrier -> no vmcnt(0) in loop.
__global__ __launch_bounds__(256, 2) void k_attn(const __bf16* __restrict__ xcat,
                                                 const __bf16* __restrict__ e_t2,
                                                 __bf16* __restrict__ Op,
                                                 float* __restrict__ Lp) {
  __shared__ __align__(16) __bf16 sT[3][8192];    // 3 x 16KB e-tile buffers
  __shared__ __align__(16) __bf16 sP[4][2][640];  // per-wave P transpose, stride 40

  const int tid  = threadIdx.x;
  const int lane = tid & 63;
  const int w    = tid >> 6;        // 0..3 -> 32-t group
  const int q    = lane >> 4;
  const int tl   = lane & 15;
  const int b    = blockIdx.x & 7;                          // XCD-pinned batch
  const int xt   = (blockIdx.x >> 3) | (blockIdx.y << 1);   // logical t-block 0..15
  const int z    = blockIdx.z;      // s-quarter
  const int tbase = xt * 128 + w * 32;

  const __bf16* etb = e_t2 + (size_t)b * TE * D;   // [64 stile][8192]

  // loop-invariant query fragments (B-operand of phase 1), 2 t-tiles
  bf16x8 cB[2][8];
#pragma unroll
  for (int tt = 0; tt < 2; ++tt) {
    const __bf16* crow = xcat + ((size_t)(b * TC) + tbase + tt * 16 + tl) * XR + q * 8;
#pragma unroll
    for (int ks = 0; ks < 8; ++ks) cB[tt][ks] = *(const bf16x8*)(crow + ks * 32);
  }

  // staging offsets: tile is a linear 16KB copy; each wave stages 4KB
  unsigned offT[4];
#pragma unroll
  for (int c = 0; c < 4; ++c) offT[c] = ((w * 4 + c) * 64 + lane) * 8;

  f32x4 accO[2][16];
#pragma unroll
  for (int tt = 0; tt < 2; ++tt)
#pragma unroll
    for (int dt = 0; dt < 16; ++dt) accO[tt][dt] = (f32x4){0.f, 0.f, 0.f, 0.f};
  float lacc[2] = {0.f, 0.f};

  const int sbase = z * (TE / 4);

  auto stage = [&](int buf, int s0) {
    const __bf16* src = etb + (size_t)(s0 >> 5) * 8192;
#pragma unroll
    for (int c = 0; c < 4; ++c)
      gl_lds16(src + offT[c], &sT[buf][(w * 4 + c) * 512]);
  };

  stage(0, sbase);
  stage(1, sbase + 32);
  WAIT_VMCNT(4);                    // cB + stage(0) done; stage(1) may fly
  BARRIER();

  // per-lane invariants
  const int p1off = (q >> 1) * 256 + tl * 16 + (q & 1) * 8;       // phase-1 frag offset
  const unsigned troff = 128u * (unsigned)q + 8u * (unsigned)tl;  // tr: window q, col tl

  int cur = 0;
  for (int k = 0; k < 16; ++k) {
    if (k < 14) {
      int nb = cur + 2; if (nb >= 3) nb -= 3;
      stage(nb, sbase + (k + 2) * 32);           // 4 DMA, stays in flight past barrier
    }
    const __bf16* pe = &sT[cur][0];

    // ---- phase 1: S^T for 32 s x 32 t (A from [sh][dt][s][d] subtiles) ----
    f32x4 aS[2][2];
#pragma unroll
    for (int i = 0; i < 2; ++i)
#pragma unroll
      for (int j = 0; j < 2; ++j) aS[i][j] = (f32x4){0.f, 0.f, 0.f, 0.f};
#pragma unroll
    for (int ks = 0; ks < 8; ++ks) {
      const __bf16* pa = pe + ks * 512 + p1off;
      bf16x8 a0 = *(const bf16x8*)pa;            // sh=0: s=tl
      bf16x8 a1 = *(const bf16x8*)(pa + 4096);   // sh=1: s=16+tl
      aS[0][0] = MFMA(a0, cB[0][ks], aS[0][0]);
      aS[0][1] = MFMA(a0, cB[1][ks], aS[0][1]);
      aS[1][0] = MFMA(a1, cB[0][ks], aS[1][0]);
      aS[1][1] = MFMA(a1, cB[1][ks], aS[1][1]);
    }

    // ---- exp + pack bf16, C-layout -> per-wave LDS transpose ----
#pragma unroll
    for (int tt = 0; tt < 2; ++tt) {
      bf16x4 w0, w1;
#pragma unroll
      for (int r = 0; r < 4; ++r) {
        float e0 = exp2f(aS[0][tt][r] * EXP_C);
        float e1 = exp2f(aS[1][tt][r] * EXP_C);
        lacc[tt] += e0 + e1;
        w0[r] = (__bf16)e0;
        w1[r] = (__bf16)e1;
      }
      __bf16* pw = &sP[w][tt][tl * 40 + q * 4];
      *(bf16x4*)pw = w0;          // P[s=q*4+r][t=tl]
      *(bf16x4*)(pw + 16) = w1;   // P[s=16+q*4+r][t=tl]
    }
    // P fragments in tr-matched k order: j<4 -> s=4q+j, j>=4 -> s=16+4q+(j-4)
    bf16x4 lo0 = *(const bf16x4*)(&sP[w][0][tl * 40 + q * 4]);
    bf16x4 hi0 = *(const bf16x4*)(&sP[w][0][tl * 40 + 16 + q * 4]);
    bf16x4 lo1 = *(const bf16x4*)(&sP[w][1][tl * 40 + q * 4]);
    bf16x4 hi1 = *(const bf16x4*)(&sP[w][1][tl * 40 + 16 + q * 4]);
    bf16x8 pB0, pB1;
#pragma unroll
    for (int r = 0; r < 4; ++r) {
      pB0[r] = lo0[r]; pB0[4 + r] = hi0[r];
      pB1[r] = lo1[r]; pB1[4 + r] = hi1[r];
    }

    // ---- phase 2: O^T accumulate via tr-reads, 4 groups of 4 d-tiles ----
    const unsigned abase = (unsigned)(uintptr_t)pe + troff;
#pragma unroll
    for (int g = 0; g < 4; ++g) {
      bf16x4 t0[4], t1[4];
#pragma unroll
      for (int d4 = 0; d4 < 4; ++d4) {
        const unsigned o = abase + (unsigned)((g * 4 + d4) * 512);
        t0[d4] = tr_b64(o);           // sh=0: s=4q+j, d=dt*16+tl
        t1[d4] = tr_b64(o + 8192u);   // sh=1: s=16+4q+j
      }
      asm volatile("s_waitcnt lgkmcnt(0)" ::: "memory");
      __builtin_amdgcn_sched_barrier(0);         // rule #18: no MFMA hoisting
#pragma unroll
      for (int d4 = 0; d4 < 4; ++d4) {
        const int dt = g * 4 + d4;
        bf16x8 af;
#pragma unroll
        for (int r = 0; r < 4; ++r) { af[r] = t0[d4][r]; af[4 + r] = t1[d4][r]; }
        accO[0][dt] = MFMA(af, pB0, accO[0][dt]);
        accO[1][dt] = MFMA(af, pB1, accO[1][dt]);
      }
    }

    // counted publish: stage(k+1) landed for THIS wave; barrier makes it landed
    // for ALL waves before anyone reads buf k+1. stage(k+2) stays in flight.
    if (k < 14)      WAIT_VMCNT(4);
    else if (k == 14) WAIT_VMCNT(0);
    if (k < 15) BARRIER();
    cur += 1; if (cur == 3) cur = 0;
  }

  // ---- per-wave epilogue: z-interleaved partial O/L ----
#pragma unroll
  for (int tt = 0; tt < 2; ++tt) {
    float v = lacc[tt];
    v += __shfl_xor(v, 16, 64);
    v += __shfl_xor(v, 32, 64);
    const size_t rowl = (size_t)b * TC + tbase + tt * 16 + tl;
    if (q == 0) Lp[rowl * 4 + z] = v;
    __bf16* orow = Op + (rowl * 4 + z) * D + q * 4;
#pragma unroll
    for (int dt = 0; dt < 16; ++dt) {
      bf16x4 o;
#pragma unroll
      for (int r = 0; r < 4; ++r) o[r] = (__bf16)accO[tt][dt][r];
      *(bf16x4*)(orow + dt * 16) = o;
    }
  }
}

// ---- conv1d as LDS-staged 3-tap GEMM, z-combine fused (Tt=64) -- UNCHANGED R5 ----
__global__ __launch_bounds__(512, 2) void k_conv(const __bf16* __restrict__ xcat,
                                                 const __bf16* __restrict__ Op,
                                                 const float* __restrict__ Lp,
                                                 const __bf16* __restrict__ Wk,
                                                 const float* __restrict__ bias,
                                                 float* __restrict__ out) {
  __shared__ __align__(16) __bf16 sXA[66 * 256];   // content half, rows t0-1..t0+64
  __shared__ __align__(16) __bf16 sXB[66 * 256];   // normalized attn half
  __shared__ __align__(16) __bf16 sW[3][8192];     // row o, slot ps -> p=ps^((o>>2)&3)
  const int tid  = threadIdx.x;
  const int lane = tid & 63;
  const int wv   = tid >> 6;        // 0..7
  const int wo   = wv & 3;          // o-group (64 o)
  const int wt   = wv >> 2;         // t-half (32 t)
  const int q    = lane >> 4;
  const int tl   = lane & 15;
  const int b    = blockIdx.x & 7;  // XCD-pinned batch
  const int t0   = (blockIdx.x >> 3) * 64;
  const int o0   = wo * 64;
  const int sw3  = (tl >> 2) & 3;
  const int rh   = lane >> 5;       // row-within-pair for staging
  const int l5   = lane & 31;

  // ---- plane A: DMA 2 rows per instruction, swizzled global source ----
  const __bf16* xb = xcat + (size_t)b * TC * XR;
  for (int i = wv; i < 33; i += 8) {
    const int rl = 2 * i + rh;                   // local row 0..65
    int gr = t0 - 1 + rl;
    gr = gr < 0 ? 0 : (gr > TC - 1 ? TC - 1 : gr);
    const int cs = l5 ^ (rl & 7);                // 16B-chunk index, pre-swizzled
    gl_lds16(xb + (size_t)gr * XR + cs * 8, &sXA[i * 512]);
  }

  // ---- weight staging offsets (swizzled, 64B-coalesced per o-row) ----
  unsigned offW[2];
#pragma unroll
  for (int c = 0; c < 2; ++c) {
    const int id = (wv * 2 + c) * 64 + lane;     // 0..1023
    const int o = id >> 2, ps = id & 3;
    offW[c] = o * 512 + (ps ^ ((o >> 2) & 3)) * 8;
  }
  auto stageW = [&](int buf, int s) {
    const int kk = s >> 4, is = s & 15;
    const __bf16* wb = Wk + (size_t)kk * TGT * 512 + is * 32;
#pragma unroll
    for (int c = 0; c < 2; ++c)
      gl_lds16(wb + offW[c], &sW[buf][(wv * 2 + c) * 512]);
  };
  stageW(0, 0);
  stageW(1, 1);

  // ---- plane B: combine 4 z-partials + normalize, swizzled ds_write ----
  for (int i = wv; i < 33; i += 8) {
    const int rl = 2 * i + rh;
    int gr = t0 - 1 + rl;
    gr = gr < 0 ? 0 : (gr > TC - 1 ? TC - 1 : gr);
    const size_t row = (size_t)b * TC + gr;
    const float4 lv = *(const float4*)(Lp + row * 4);
    const float inv = 1.0f / (lv.x + lv.y + lv.z + lv.w);
    float a8[8] = {0.f, 0.f, 0.f, 0.f, 0.f, 0.f, 0.f, 0.f};
#pragma unroll
    for (int zz = 0; zz < 4; ++zz) {
      bf16x8 a = *(const bf16x8*)(Op + (row * 4 + zz) * D + l5 * 8);
#pragma unroll
      for (int r = 0; r < 8; ++r) a8[r] += (float)a[r];
    }
    bf16x8 o;
#pragma unroll
    for (int r = 0; r < 8; ++r) o[r] = (__bf16)(a8[r] * inv);
    *(bf16x8*)((char*)&sXB[rl * 256] + ((l5 * 16) ^ ((rl & 7) << 4))) = o;
  }

  DRAIN_VMCNT();                    // prologue: full drain is fine (once)
  __syncthreads();

  // halo rows: replace clamped duplicates with zeros (conv zero-padding)
  if (t0 == 0 && tid < 256) { sXA[tid] = (__bf16)0.f; sXB[tid] = (__bf16)0.f; }
  if (t0 + 64 == TC && tid < 256) {
    sXA[65 * 256 + tid] = (__bf16)0.f; sXB[65 * 256 + tid] = (__bf16)0.f;
  }
  __syncthreads();

  f32x4 acc[4][2];
#pragma unroll
  for (int mt = 0; mt < 4; ++mt) {
#pragma unroll
    for (int r = 0; r < 4; ++r) {
      const float bv = bias[o0 + mt * 16 + q * 4 + r];
#pragma unroll
      for (int nt = 0; nt < 2; ++nt) acc[mt][nt][r] = bv;
    }
  }

  int cur = 0;                      // buf index = s % 3
  for (int s = 0; s < 48; ++s) {
    if (s < 46) stageW((cur + 2) % 3, s + 2);    // keep 2 stages in flight
    const int kk = s >> 4, is = s & 15;
    const __bf16* pl = (is & 8) ? sXB : sXA;     // ch 256:512 -> plane B
    const int cbyte = (is & 7) * 64 + q * 16;    // byte col base within plane
    bf16x8 bfr[2];
#pragma unroll
    for (int nt = 0; nt < 2; ++nt) {
      const int t = wt * 32 + nt * 16 + tl + kk;
      bfr[nt] = *(const bf16x8*)((const char*)pl + t * 512 + (cbyte ^ ((t & 7) << 4)));
    }
#pragma unroll
    for (int mt = 0; mt < 4; ++mt) {
      const int o = o0 + mt * 16 + tl;
      bf16x8 af = *(const bf16x8*)(&sW[cur][(o * 4 + (q ^ sw3)) * 8]);
#pragma unroll
      for (int nt = 0; nt < 2; ++nt) acc[mt][nt] = MFMA(af, bfr[nt], acc[mt][nt]);
    }
    if (s < 46) WAIT_VMCNT_2(); else DRAIN_VMCNT();
    __builtin_amdgcn_s_barrier();
    __builtin_amdgcn_sched_barrier(0);           // no ds_read hoisting across barrier
    cur = cur == 2 ? 0 : cur + 1;
  }

#pragma unroll
  for (int mt = 0; mt < 4; ++mt) {
#pragma unroll
    for (int nt = 0; nt < 2; ++nt) {
#pragma unroll
      for (int r = 0; r < 4; ++r) {
        const int o = o0 + mt * 16 + q * 4 + r;
        const int t = t0 + wt * 32 + nt * 16 + tl;
        out[((size_t)b * TGT + o) * TC + t] = acc[mt][nt][r];
      }
    }
  }
}

extern "C" void kernel_launch(void* const* d_in, const int* in_sizes, int n_in,
                              void* d_out, int out_size, void* d_ws, size_t ws_size,
                              hipStream_t stream) {
  (void)in_sizes; (void)n_in; (void)out_size; (void)ws_size;
  const float* content = (const float*)d_in[0];  // fp32 [B][256][2048]
  const float* emotion = (const float*)d_in[1];  // fp32 [B][256][2048]
  const float* conv_w  = (const float*)d_in[2];  // fp32 [256][512][3]
  const float* conv_b  = (const float*)d_in[3];  // fp32 [256]
  float* out = (float*)d_out;                    // fp32 [B][256][2048]

  char* ws = (char*)d_ws;
  __bf16* xcat = (__bf16*)ws;                          //  8,388,608 B
  __bf16* Wk   = (__bf16*)(ws + 8388608);              //    786,432 B
  __bf16* Op   = (__bf16*)(ws + 9437184);              // 33,554,432 B (z-interleaved)
  float*  Lp   = (float*)(ws + 42991616);              //    262,144 B (total 43.3 MB)
  // e_t2 lives in d_out (8,388,608 B); consumed by k_attn before k_conv writes out.
  __bf16* e_t2 = (__bf16*)d_out;                       // bf16 [B][64][8192]

  k_prep_all<<<dim3(Bc, TC / 64 + 1, 8), 256, 0, stream>>>(
      content, emotion, xcat, e_t2, conv_w, Wk);
  k_attn<<<dim3(TC / 128, Bc, 4), 256, 0, stream>>>(xcat, e_t2, Op, Lp);
  k_conv<<<dim3((TC / 64) * Bc), 512, 0, stream>>>(xcat, Op, Lp, Wk, conv_b, out);
}

// Round 8
// 162.903 us; speedup vs baseline: 1.0604x; 1.0266x over previous
//
#include <hip/hip_runtime.h>

typedef __bf16 bf16x8 __attribute__((ext_vector_type(8)));
typedef __bf16 bf16x4 __attribute__((ext_vector_type(4)));
typedef float  f32x4  __attribute__((ext_vector_type(4)));

#define MFMA(a, b, c) __builtin_amdgcn_mfma_f32_16x16x32_bf16((a), (b), (c), 0, 0, 0)
// gfx9 s_waitcnt encodings: [3:0]=vmcnt(low), [6:4]=expcnt(7=nowait), [11:8]=lgkm(0xF=nowait)
#define WAIT_VMCNT(n)  __builtin_amdgcn_s_waitcnt(0x0F70 | (n))
#define DRAIN_VMCNT()  __builtin_amdgcn_s_waitcnt(0x0F70)
#define WAIT_VMCNT_2() __builtin_amdgcn_s_waitcnt(0x0F72)
// raw barrier (no vmcnt(0) drain) + scheduler fence
#define BARRIER() do { __builtin_amdgcn_s_barrier(); __builtin_amdgcn_sched_barrier(0); } while (0)

constexpr int Bc  = 8;
constexpr int D   = 256;
constexpr int TC  = 2048;
constexpr int TE  = 2048;
constexpr int TGT = 256;
constexpr int XR  = 256;            // xcat row stride (content half only)

// exp(x/16) == exp2(x * log2(e)/16)
#define EXP_C 0.09016844005556021f

// async global->LDS, 16B per lane; LDS dst = base + lane*16 (wave-uniform base)
__device__ __forceinline__ void gl_lds16(const __bf16* g, __bf16* l) {
  __builtin_amdgcn_global_load_lds(
      (const __attribute__((address_space(1))) void*)g,
      (__attribute__((address_space(3))) void*)l, 16, 0, 0);
}

// hardware transpose read: lane receives the 4 bf16 at bytes {addr, +32, +64, +96}
// (empirically validated by R7-pass with the {4q+j,16+4q+j} k-order pairing)
__device__ __forceinline__ bf16x4 tr_b64(unsigned addr) {
  bf16x4 d;
  asm volatile("ds_read_b64_tr_b16 %0, %1" : "=v"(d) : "v"(addr));
  return d;
}

// ---- fused prep: content transpose + emotion subtile-pack + weight repack ----
// XCD-PINNED grid (Bc, TC/64 + 1, 8): linear id = x + 8*(y + 33*z) -> XCD = x = b.
//   y < 32, z < 4 : content fp32 [B][D][TC] -> xcat bf16 [B][TC][256]
//   y < 32, z >= 4: emotion fp32 [B][D][TE] -> e_t2 bf16 [B][64 stile][2 sh][16 dt][16 s][16 d]
//                   (exact LDS tile image: one 16KB contiguous block per 32-s tile)
//   y == 32       : conv weight fp32 [256][512][3] -> Wk bf16 [3][256][512]
__global__ void k_prep_all(const float* __restrict__ content,
                           const float* __restrict__ emotion,
                           __bf16* __restrict__ xcat, __bf16* __restrict__ e_t2,
                           const float* __restrict__ w, __bf16* __restrict__ Wk) {
  __shared__ __bf16 tile[64][68];
  const int tid = threadIdx.x;

  if (blockIdx.y == TC / 64) {       // ---- weight repack: 64 blocks x 2048 idx ----
    const int base = (blockIdx.z * 8 + blockIdx.x) * 2048;
#pragma unroll
    for (int j = 0; j < 8; ++j) {
      const int idx = base + j * 256 + tid;   // o*512 + i
      const int o = idx >> 9, i = idx & 511;
#pragma unroll
      for (int k = 0; k < 3; ++k)
        Wk[k * (TGT * 512) + idx] = (__bf16)w[(size_t)o * 1536 + i * 3 + k];
    }
    return;
  }

  const int b   = blockIdx.x;        // == XCD id
  const int t0  = blockIdx.y * 64;
  const int sec = blockIdx.z;
  const bool isC = sec < 4;
  const int d0 = (sec & 3) * 64;
  const int c4 = (tid & 15) * 4;
  const int r0 = tid >> 4;          // 0..15
  const float* sp = (isC ? content : emotion) + ((size_t)b * D + d0) * 2048 + t0;
#pragma unroll
  for (int i = 0; i < 4; ++i) {
    const int r = r0 + 16 * i;
    const float4 v = *(const float4*)(sp + (size_t)r * 2048 + c4);
    bf16x4 pv;
    pv[0] = (__bf16)v.x; pv[1] = (__bf16)v.y; pv[2] = (__bf16)v.z; pv[3] = (__bf16)v.w;
    *(bf16x4*)&tile[r][c4] = pv;
  }
  __syncthreads();

  if (isC) {
    // tile[d][t] -> xcat rows t, 8 d per lane, 16B stores (stride 256)
    __bf16* dp = xcat + ((size_t)b * TC + t0) * XR + d0;
#pragma unroll
    for (int i = 0; i < 2; ++i) {
      const int idx = tid + 256 * i;  // 0..511
      const int r   = idx >> 3;       // t-local 0..63
      const int c8  = (idx & 7) * 8;  // d-local chunk
      bf16x8 v;
#pragma unroll
      for (int j = 0; j < 8; ++j) v[j] = tile[c8 + j][r];
      *(bf16x8*)(dp + (size_t)r * 256 + c8) = v;
    }
  } else {
    // e_t2 subtile pack: value e[s=t0+r][d=d0+dc*8+j] ->
    //   [stile][sh][dt][s&15][d&15], stile=(t0+r)>>5, sh=(r>>4)&1, dt=(d0>>4)+(dc>>1)
    __bf16* base = e_t2 + (size_t)b * TE * D + (size_t)(t0 >> 5) * 8192
                   + (size_t)(d0 >> 4) * 256;
#pragma unroll
    for (int i = 0; i < 2; ++i) {
      const int idx = tid + 256 * i;
      const int r   = idx >> 3;       // s-local 0..63
      const int dc  = idx & 7;        // d chunk of 8
      bf16x8 v;
#pragma unroll
      for (int j = 0; j < 8; ++j) v[j] = tile[dc * 8 + j][r];
      __bf16* qp = base + (r >> 5) * 8192
                   + ((((r >> 4) & 1) * 16 + (dc >> 1)) * 16 + (r & 15)) * 16
                   + (dc & 1) * 8;
      *(bf16x8*)qp = v;
    }
  }
}

// ---- flash attention: tr-read PV + fully in-register softmax ----
// Key identity (R8): with the tr-matched k-order {4q+j, 16+4q+j}, the P fragment
// each lane needs for PV's B-operand is EXACTLY the S elements that lane owns in
// the phase-1 C-layout (row = 4q+r+16sh, col = tl). So P never leaves registers:
// pB[j] = (bf16)exp2(aS[sh][tt][j]*c). No sP LDS transpose, no lgkm serialization.
// Pipeline: 3-buf, stage(k+2) each step, end-of-step vmcnt(4) + raw s_barrier
// (stage k+1 landed for all waves; k+2 stays in flight). No vmcnt(0) in loop.
__global__ __launch_bounds__(256, 2) void k_attn(const __bf16* __restrict__ xcat,
                                                 const __bf16* __restrict__ e_t2,
                                                 __bf16* __restrict__ Op,
                                                 float* __restrict__ Lp) {
  __shared__ __align__(16) __bf16 sT[3][8192];    // 3 x 16KB e-tile buffers

  const int tid  = threadIdx.x;
  const int lane = tid & 63;
  const int w    = tid >> 6;        // 0..3 -> 32-t group
  const int q    = lane >> 4;
  const int tl   = lane & 15;
  const int b    = blockIdx.x & 7;                          // XCD-pinned batch
  const int xt   = (blockIdx.x >> 3) | (blockIdx.y << 1);   // logical t-block 0..15
  const int z    = blockIdx.z;      // s-quarter
  const int tbase = xt * 128 + w * 32;

  const __bf16* etb = e_t2 + (size_t)b * TE * D;   // [64 stile][8192]

  // loop-invariant query fragments (B-operand of phase 1), 2 t-tiles
  bf16x8 cB[2][8];
#pragma unroll
  for (int tt = 0; tt < 2; ++tt) {
    const __bf16* crow = xcat + ((size_t)(b * TC) + tbase + tt * 16 + tl) * XR + q * 8;
#pragma unroll
    for (int ks = 0; ks < 8; ++ks) cB[tt][ks] = *(const bf16x8*)(crow + ks * 32);
  }

  // staging offsets: tile is a linear 16KB copy; each wave stages 4KB
  unsigned offT[4];
#pragma unroll
  for (int c = 0; c < 4; ++c) offT[c] = ((w * 4 + c) * 64 + lane) * 8;

  f32x4 accO[2][16];
#pragma unroll
  for (int tt = 0; tt < 2; ++tt)
#pragma unroll
    for (int dt = 0; dt < 16; ++dt) accO[tt][dt] = (f32x4){0.f, 0.f, 0.f, 0.f};
  float lacc[2] = {0.f, 0.f};

  const int sbase = z * (TE / 4);

  auto stage = [&](int buf, int s0) {
    const __bf16* src = etb + (size_t)(s0 >> 5) * 8192;
#pragma unroll
    for (int c = 0; c < 4; ++c)
      gl_lds16(src + offT[c], &sT[buf][(w * 4 + c) * 512]);
  };

  stage(0, sbase);
  stage(1, sbase + 32);
  WAIT_VMCNT(4);                    // cB + stage(0) done; stage(1) may fly
  BARRIER();

  // per-lane invariants
  const int p1off = (q >> 1) * 256 + tl * 16 + (q & 1) * 8;       // phase-1 frag offset
  const unsigned troff = 128u * (unsigned)q + 8u * (unsigned)tl;  // tr read offset

  int cur = 0;
  for (int k = 0; k < 16; ++k) {
    if (k < 14) {
      int nb = cur + 2; if (nb >= 3) nb -= 3;
      stage(nb, sbase + (k + 2) * 32);           // 4 DMA, stays in flight past barrier
    }
    const __bf16* pe = &sT[cur][0];

    // ---- phase 1: S^T for 32 s x 32 t (A from [sh][dt][s][d] subtiles) ----
    f32x4 aS[2][2];
#pragma unroll
    for (int i = 0; i < 2; ++i)
#pragma unroll
      for (int j = 0; j < 2; ++j) aS[i][j] = (f32x4){0.f, 0.f, 0.f, 0.f};
#pragma unroll
    for (int ks = 0; ks < 8; ++ks) {
      const __bf16* pa = pe + ks * 512 + p1off;
      bf16x8 a0 = *(const bf16x8*)pa;            // sh=0: s=tl
      bf16x8 a1 = *(const bf16x8*)(pa + 4096);   // sh=1: s=16+tl
      aS[0][0] = MFMA(a0, cB[0][ks], aS[0][0]);
      aS[0][1] = MFMA(a0, cB[1][ks], aS[0][1]);
      aS[1][0] = MFMA(a1, cB[0][ks], aS[1][0]);
      aS[1][1] = MFMA(a1, cB[1][ks], aS[1][1]);
    }

    // ---- softmax fully in-register: lane (q,tl) owns S rows {4q+r, 16+4q+r} at
    // col tl == exactly the k-slots {j, 4+j} of its PV B-fragment. Zero shuffles.
    bf16x8 pB0, pB1;
#pragma unroll
    for (int r = 0; r < 4; ++r) {
      const float e00 = exp2f(aS[0][0][r] * EXP_C);
      const float e10 = exp2f(aS[1][0][r] * EXP_C);
      const float e01 = exp2f(aS[0][1][r] * EXP_C);
      const float e11 = exp2f(aS[1][1][r] * EXP_C);
      lacc[0] += e00 + e10;
      lacc[1] += e01 + e11;
      pB0[r] = (__bf16)e00; pB0[4 + r] = (__bf16)e10;
      pB1[r] = (__bf16)e01; pB1[4 + r] = (__bf16)e11;
    }

    // ---- phase 2: O^T accumulate via tr-reads, 4 groups of 4 d-tiles ----
    const unsigned abase = (unsigned)(uintptr_t)pe + troff;
#pragma unroll
    for (int g = 0; g < 4; ++g) {
      bf16x4 t0[4], t1[4];
#pragma unroll
      for (int d4 = 0; d4 < 4; ++d4) {
        const unsigned o = abase + (unsigned)((g * 4 + d4) * 512);
        t0[d4] = tr_b64(o);           // sh=0: s=4q+j, d=dt*16+tl
        t1[d4] = tr_b64(o + 8192u);   // sh=1: s=16+4q+j
      }
      asm volatile("s_waitcnt lgkmcnt(0)" ::: "memory");
      __builtin_amdgcn_sched_barrier(0);         // rule #18: no MFMA hoisting
#pragma unroll
      for (int d4 = 0; d4 < 4; ++d4) {
        const int dt = g * 4 + d4;
        bf16x8 af;
#pragma unroll
        for (int r = 0; r < 4; ++r) { af[r] = t0[d4][r]; af[4 + r] = t1[d4][r]; }
        accO[0][dt] = MFMA(af, pB0, accO[0][dt]);
        accO[1][dt] = MFMA(af, pB1, accO[1][dt]);
      }
    }

    // counted publish: stage(k+1) landed for THIS wave; barrier makes it landed
    // for ALL waves before anyone reads buf k+1. stage(k+2) stays in flight.
    if (k < 14)      WAIT_VMCNT(4);
    else if (k == 14) WAIT_VMCNT(0);
    if (k < 15) BARRIER();
    cur += 1; if (cur == 3) cur = 0;
  }

  // ---- per-wave epilogue: z-interleaved partial O/L ----
#pragma unroll
  for (int tt = 0; tt < 2; ++tt) {
    float v = lacc[tt];
    v += __shfl_xor(v, 16, 64);
    v += __shfl_xor(v, 32, 64);
    const size_t rowl = (size_t)b * TC + tbase + tt * 16 + tl;
    if (q == 0) Lp[rowl * 4 + z] = v;
    __bf16* orow = Op + (rowl * 4 + z) * D + q * 4;
#pragma unroll
    for (int dt = 0; dt < 16; ++dt) {
      bf16x4 o;
#pragma unroll
      for (int r = 0; r < 4; ++r) o[r] = (__bf16)accO[tt][dt][r];
      *(bf16x4*)(orow + dt * 16) = o;
    }
  }
}

// ---- conv1d as LDS-staged 3-tap GEMM, z-combine fused (Tt=64) -- UNCHANGED R7 ----
__global__ __launch_bounds__(512, 2) void k_conv(const __bf16* __restrict__ xcat,
                                                 const __bf16* __restrict__ Op,
                                                 const float* __restrict__ Lp,
                                                 const __bf16* __restrict__ Wk,
                                                 const float* __restrict__ bias,
                                                 float* __restrict__ out) {
  __shared__ __align__(16) __bf16 sXA[66 * 256];   // content half, rows t0-1..t0+64
  __shared__ __align__(16) __bf16 sXB[66 * 256];   // normalized attn half
  __shared__ __align__(16) __bf16 sW[3][8192];     // row o, slot ps -> p=ps^((o>>2)&3)
  const int tid  = threadIdx.x;
  const int lane = tid & 63;
  const int wv   = tid >> 6;        // 0..7
  const int wo   = wv & 3;          // o-group (64 o)
  const int wt   = wv >> 2;         // t-half (32 t)
  const int q    = lane >> 4;
  const int tl   = lane & 15;
  const int b    = blockIdx.x & 7;  // XCD-pinned batch
  const int t0   = (blockIdx.x >> 3) * 64;
  const int o0   = wo * 64;
  const int sw3  = (tl >> 2) & 3;
  const int rh   = lane >> 5;       // row-within-pair for staging
  const int l5   = lane & 31;

  // ---- plane A: DMA 2 rows per instruction, swizzled global source ----
  const __bf16* xb = xcat + (size_t)b * TC * XR;
  for (int i = wv; i < 33; i += 8) {
    const int rl = 2 * i + rh;                   // local row 0..65
    int gr = t0 - 1 + rl;
    gr = gr < 0 ? 0 : (gr > TC - 1 ? TC - 1 : gr);
    const int cs = l5 ^ (rl & 7);                // 16B-chunk index, pre-swizzled
    gl_lds16(xb + (size_t)gr * XR + cs * 8, &sXA[i * 512]);
  }

  // ---- weight staging offsets (swizzled, 64B-coalesced per o-row) ----
  unsigned offW[2];
#pragma unroll
  for (int c = 0; c < 2; ++c) {
    const int id = (wv * 2 + c) * 64 + lane;     // 0..1023
    const int o = id >> 2, ps = id & 3;
    offW[c] = o * 512 + (ps ^ ((o >> 2) & 3)) * 8;
  }
  auto stageW = [&](int buf, int s) {
    const int kk = s >> 4, is = s & 15;
    const __bf16* wb = Wk + (size_t)kk * TGT * 512 + is * 32;
#pragma unroll
    for (int c = 0; c < 2; ++c)
      gl_lds16(wb + offW[c], &sW[buf][(wv * 2 + c) * 512]);
  };
  stageW(0, 0);
  stageW(1, 1);

  // ---- plane B: combine 4 z-partials + normalize, swizzled ds_write ----
  for (int i = wv; i < 33; i += 8) {
    const int rl = 2 * i + rh;
    int gr = t0 - 1 + rl;
    gr = gr < 0 ? 0 : (gr > TC - 1 ? TC - 1 : gr);
    const size_t row = (size_t)b * TC + gr;
    const float4 lv = *(const float4*)(Lp + row * 4);
    const float inv = 1.0f / (lv.x + lv.y + lv.z + lv.w);
    float a8[8] = {0.f, 0.f, 0.f, 0.f, 0.f, 0.f, 0.f, 0.f};
#pragma unroll
    for (int zz = 0; zz < 4; ++zz) {
      bf16x8 a = *(const bf16x8*)(Op + (row * 4 + zz) * D + l5 * 8);
#pragma unroll
      for (int r = 0; r < 8; ++r) a8[r] += (float)a[r];
    }
    bf16x8 o;
#pragma unroll
    for (int r = 0; r < 8; ++r) o[r] = (__bf16)(a8[r] * inv);
    *(bf16x8*)((char*)&sXB[rl * 256] + ((l5 * 16) ^ ((rl & 7) << 4))) = o;
  }

  DRAIN_VMCNT();                    // prologue: full drain is fine (once)
  __syncthreads();

  // halo rows: replace clamped duplicates with zeros (conv zero-padding)
  if (t0 == 0 && tid < 256) { sXA[tid] = (__bf16)0.f; sXB[tid] = (__bf16)0.f; }
  if (t0 + 64 == TC && tid < 256) {
    sXA[65 * 256 + tid] = (__bf16)0.f; sXB[65 * 256 + tid] = (__bf16)0.f;
  }
  __syncthreads();

  f32x4 acc[4][2];
#pragma unroll
  for (int mt = 0; mt < 4; ++mt) {
#pragma unroll
    for (int r = 0; r < 4; ++r) {
      const float bv = bias[o0 + mt * 16 + q * 4 + r];
#pragma unroll
      for (int nt = 0; nt < 2; ++nt) acc[mt][nt][r] = bv;
    }
  }

  int cur = 0;                      // buf index = s % 3
  for (int s = 0; s < 48; ++s) {
    if (s < 46) stageW((cur + 2) % 3, s + 2);    // keep 2 stages in flight
    const int kk = s >> 4, is = s & 15;
    const __bf16* pl = (is & 8) ? sXB : sXA;     // ch 256:512 -> plane B
    const int cbyte = (is & 7) * 64 + q * 16;    // byte col base within plane
    bf16x8 bfr[2];
#pragma unroll
    for (int nt = 0; nt < 2; ++nt) {
      const int t = wt * 32 + nt * 16 + tl + kk;
      bfr[nt] = *(const bf16x8*)((const char*)pl + t * 512 + (cbyte ^ ((t & 7) << 4)));
    }
#pragma unroll
    for (int mt = 0; mt < 4; ++mt) {
      const int o = o0 + mt * 16 + tl;
      bf16x8 af = *(const bf16x8*)(&sW[cur][(o * 4 + (q ^ sw3)) * 8]);
#pragma unroll
      for (int nt = 0; nt < 2; ++nt) acc[mt][nt] = MFMA(af, bfr[nt], acc[mt][nt]);
    }
    if (s < 46) WAIT_VMCNT_2(); else DRAIN_VMCNT();
    __builtin_amdgcn_s_barrier();
    __builtin_amdgcn_sched_barrier(0);           // no ds_read hoisting across barrier
    cur = cur == 2 ? 0 : cur + 1;
  }

#pragma unroll
  for (int mt = 0; mt < 4; ++mt) {
#pragma unroll
    for (int nt = 0; nt < 2; ++nt) {
#pragma unroll
      for (int r = 0; r < 4; ++r) {
        const int o = o0 + mt * 16 + q * 4 + r;
        const int t = t0 + wt * 32 + nt * 16 + tl;
        out[((size_t)b * TGT + o) * TC + t] = acc[mt][nt][r];
      }
    }
  }
}

extern "C" void kernel_launch(void* const* d_in, const int* in_sizes, int n_in,
                              void* d_out, int out_size, void* d_ws, size_t ws_size,
                              hipStream_t stream) {
  (void)in_sizes; (void)n_in; (void)out_size; (void)ws_size;
  const float* content = (const float*)d_in[0];  // fp32 [B][256][2048]
  const float* emotion = (const float*)d_in[1];  // fp32 [B][256][2048]
  const float* conv_w  = (const float*)d_in[2];  // fp32 [256][512][3]
  const float* conv_b  = (const float*)d_in[3];  // fp32 [256]
  float* out = (float*)d_out;                    // fp32 [B][256][2048]

  char* ws = (char*)d_ws;
  __bf16* xcat = (__bf16*)ws;                          //  8,388,608 B
  __bf16* Wk   = (__bf16*)(ws + 8388608);              //    786,432 B
  __bf16* Op   = (__bf16*)(ws + 9437184);              // 33,554,432 B (z-interleaved)
  float*  Lp   = (float*)(ws + 42991616);              //    262,144 B (total 43.3 MB)
  // e_t2 lives in d_out (8,388,608 B); consumed by k_attn before k_conv writes out.
  __bf16* e_t2 = (__bf16*)d_out;                       // bf16 [B][64][8192]

  k_prep_all<<<dim3(Bc, TC / 64 + 1, 8), 256, 0, stream>>>(
      content, emotion, xcat, e_t2, conv_w, Wk);
  k_attn<<<dim3(TC / 128, Bc, 4), 256, 0, stream>>>(xcat, e_t2, Op, Lp);
  k_conv<<<dim3((TC / 64) * Bc), 512, 0, stream>>>(xcat, Op, Lp, Wk, conv_b, out);
}